// Round 5
// baseline (1359.436 us; speedup 1.0000x reference)
//
#include <hip/hip_runtime.h>
#include <cstdint>
#include <cstddef>

#define H2 1024
#define TT 512
#define NSTEPS 64

using floatx4 = __attribute__((__ext_vector_type__(4))) float;
using half8   = __attribute__((__ext_vector_type__(8))) _Float16;
using half4   = __attribute__((__ext_vector_type__(4))) _Float16;

__device__ __forceinline__ float tanh_fast(float x) {
  return 1.0f - 2.0f / (__expf(2.0f * x) + 1.0f);
}

#define GLDS16(gp, lp)                                                         \
  __builtin_amdgcn_global_load_lds(                                            \
      (const __attribute__((address_space(1))) void*)(gp),                     \
      (__attribute__((address_space(3))) void*)(lp), 16, 0, 0)

#define SENTINEL 0xFFFFFFFFu  // -NaN bit pattern; never produced by the math

union ShMem {
  float t[64 * 69];            // phase-1 transpose tile (17.7 KB)
  struct {
    _Float16 A[256 * 64];      // 32 KB  A tile: 256 e-rows x 64 k (swizzled)
    _Float16 B[32 * 64];       // 4 KB   B tile: 32 t-rows x 64 k (swizzled)
    char pad[512];
    float bias[H2];            // 4 KB (disjoint from phase-1 t[] region)
  } p2;
};

// ---------------------------------------------------------------------------
// Mega kernel. blocks 0..31: recurrence (sentinel-poll, no cross-block waits
// on gemm). blocks 32..287: per (n, 128-t slice): transpose h -> hhT fp16,
// then t-chunked GEMM computing tanh(W h + b) fp16, written in-place over own
// hhT rows AFTER each t-chunk's last read (alias-free). All 288 blocks
// co-resident (2/CU cap) -> recurrence spin can never deadlock.
// ---------------------------------------------------------------------------
__global__ __launch_bounds__(512, 2) void mega_kernel(
    const float* __restrict__ W, const float* __restrict__ bias,
    const float* __restrict__ u0, const float* __restrict__ h,
    const _Float16* __restrict__ Wh, _Float16* __restrict__ hhT,
    float* __restrict__ vbuf, float* __restrict__ norm2) {
  __shared__ ShMem sh;
  int tid = threadIdx.x;

  if (blockIdx.x < 32) {
    // ================= RECURRENCE ROLE =================
    int bid = blockIdx.x;
    int w = tid >> 6, lane = tid & 63;
    int r0 = bid * 32 + w * 4;  // wave owns rows r0..r0+3

    float4 wreg[4][4];
#pragma unroll
    for (int p = 0; p < 4; ++p) {
      const float4* wr = (const float4*)(W + ((size_t)(r0 + p) << 10) + 16 * lane);
#pragma unroll
      for (int j = 0; j < 4; ++j) wreg[p][j] = wr[j];
    }
    float bl = bias[r0 + (lane & 3)];

    for (int i = 0; i < NSTEPS; ++i) {
      float4 z[4];
      if (i == 0) {
        const float4* up = (const float4*)(u0 + 16 * lane);
#pragma unroll
        for (int j = 0; j < 4; ++j) z[j] = up[j];
      } else {
        const unsigned long long* src =
            (const unsigned long long*)(vbuf + (((size_t)(i - 1)) << 10) + 16 * lane);
        unsigned long long v[8];
        for (;;) {
          bool good = true;
#pragma unroll
          for (int j = 0; j < 8; ++j) {
            v[j] = __hip_atomic_load(src + j, __ATOMIC_RELAXED,
                                     __HIP_MEMORY_SCOPE_AGENT);
            if ((unsigned)(v[j]) == SENTINEL ||
                (unsigned)(v[j] >> 32) == SENTINEL)
              good = false;
          }
          if (__ballot(good) == ~0ull) break;
          __builtin_amdgcn_s_sleep(2);
        }
#pragma unroll
        for (int j = 0; j < 4; ++j) {
          union { unsigned long long u[2]; float4 f; } cv;
          cv.u[0] = v[2 * j];
          cv.u[1] = v[2 * j + 1];
          z[j] = cv.f;
        }
      }

      float sq = 0.f, d0 = 0.f, d1 = 0.f, d2 = 0.f, d3 = 0.f;
#pragma unroll
      for (int j = 0; j < 4; ++j) {
        float4 c = z[j];
        sq += c.x * c.x + c.y * c.y + c.z * c.z + c.w * c.w;
        float4 a;
        a = wreg[0][j]; d0 += a.x * c.x + a.y * c.y + a.z * c.z + a.w * c.w;
        a = wreg[1][j]; d1 += a.x * c.x + a.y * c.y + a.z * c.z + a.w * c.w;
        a = wreg[2][j]; d2 += a.x * c.x + a.y * c.y + a.z * c.z + a.w * c.w;
        a = wreg[3][j]; d3 += a.x * c.x + a.y * c.y + a.z * c.z + a.w * c.w;
      }
#pragma unroll
      for (int off = 1; off <= 32; off <<= 1) {
        sq += __shfl_xor(sq, off, 64);
        d0 += __shfl_xor(d0, off, 64);
        d1 += __shfl_xor(d1, off, 64);
        d2 += __shfl_xor(d2, off, 64);
        d3 += __shfl_xor(d3, off, 64);
      }
      float rs = (i == 0) ? 1.0f : 1.0f / fmaxf(sqrtf(sq), 1e-12f);
      if (bid == 0 && w == 0 && lane == 0 && i > 0) norm2[i - 1] = sq;

      if (lane < 4) {
        float d = (lane == 0) ? d0 : (lane == 1) ? d1 : (lane == 2) ? d2 : d3;
        float v = d * rs + bl;
        __hip_atomic_store(vbuf + (((size_t)i) << 10) + r0 + lane, v,
                           __ATOMIC_RELAXED, __HIP_MEMORY_SCOPE_AGENT);
      }
    }

    if (bid == 0 && w == 0) {
      const unsigned long long* src =
          (const unsigned long long*)(vbuf + (((size_t)(NSTEPS - 1)) << 10) + 16 * lane);
      unsigned long long v[8];
      for (;;) {
        bool good = true;
#pragma unroll
        for (int j = 0; j < 8; ++j) {
          v[j] = __hip_atomic_load(src + j, __ATOMIC_RELAXED,
                                   __HIP_MEMORY_SCOPE_AGENT);
          if ((unsigned)(v[j]) == SENTINEL || (unsigned)(v[j] >> 32) == SENTINEL)
            good = false;
        }
        if (__ballot(good) == ~0ull) break;
        __builtin_amdgcn_s_sleep(2);
      }
      float sq = 0.f;
#pragma unroll
      for (int j = 0; j < 8; ++j) {
        union { unsigned long long u; float f[2]; } cv;
        cv.u = v[j];
        sq += cv.f[0] * cv.f[0] + cv.f[1] * cv.f[1];
      }
#pragma unroll
      for (int off = 1; off <= 32; off <<= 1) sq += __shfl_xor(sq, off, 64);
      if (lane == 0) norm2[NSTEPS - 1] = sq;
    }
    return;
  }

  // ================= GEMM ROLE =================
  int gb = blockIdx.x - 32;  // 0..255
  int n = gb >> 2;
  int t0 = (gb & 3) * 128;
  int w = tid >> 6, lane = tid & 63;
  int q = lane >> 4, m = lane & 15;
  int we = w >> 1, wt = w & 1;  // wave grid 4e x 2t over (256e, 32t) chunk

  // bias -> LDS (region disjoint from phase-1 tile)
  sh.p2.bias[tid] = bias[tid];
  sh.p2.bias[tid + 512] = bias[tid + 512];

  // ---- Phase 1: transpose own h slice -> hhT[n][t0..t0+128][d] fp16
  _Float16* hT = hhT + (((size_t)n) << 19);
  {
    const float* hb = h + (((size_t)n) << 19);
    for (int c = 0; c < 16; ++c) {        // d-chunks of 64
      for (int th = 0; th < 2; ++th) {    // t-halves of 64
#pragma unroll
        for (int p = 0; p < 2; ++p) {
          int slot = tid + 512 * p;       // 1024 float4 slots
          int dr = slot >> 4, tc2 = (slot & 15) << 2;
          float4 v = *(const float4*)(hb + (size_t)(64 * c + dr) * TT + t0 +
                                      64 * th + tc2);
          sh.t[dr * 69 + tc2 + 0] = v.x;
          sh.t[dr * 69 + tc2 + 1] = v.y;
          sh.t[dr * 69 + tc2 + 2] = v.z;
          sh.t[dr * 69 + tc2 + 3] = v.w;
        }
        __syncthreads();
        int tr = tid >> 3, sg = tid & 7;
        half8 hv;
#pragma unroll
        for (int u = 0; u < 8; ++u)
          hv[u] = (_Float16)sh.t[(8 * sg + u) * 69 + tr];
        *(half8*)(hT + (size_t)(t0 + 64 * th + tr) * H2 + 64 * c + 8 * sg) = hv;
        __syncthreads();
      }
    }
  }

  // ---- Phase 2: t-chunked GEMM. C[e,t] = sum_d Wh[e,d] * hhT[n,t,d]
  // LDS rows 128 B (K-tile 64), 16B segment s stored at s ^ (row&7); GLDS16
  // fetches the permuted global segment per lane -> b128 frag reads 2-way.
  int Lrow = lane >> 3;                 // row within 8-row staging group
  int Lseg = (lane & 7) ^ Lrow;         // swizzled source segment

  char* lAb = (char*)sh.p2.A + (32 * w) * 128;
  char* lBb = (char*)sh.p2.B + (8 * w) * 128;

  for (int tc = 0; tc < 4; ++tc) {
    int tb = t0 + tc * 32;
    half4 uh[4][4];  // [ec][i] — only one t-chunk's worth live (16 VGPRs)

#pragma unroll 1
    for (int ec = 0; ec < 4; ++ec) {
      int e0 = ec * 256;
      floatx4 acc[4];
#pragma unroll
      for (int i = 0; i < 4; ++i) acc[i] = {0.f, 0.f, 0.f, 0.f};

      const _Float16* gA =
          Wh + (((size_t)(e0 + 32 * w + Lrow)) << 10) + Lseg * 8;
      const _Float16* gB =
          hT + (((size_t)(tb + 8 * w + Lrow)) << 10) + Lseg * 8;

#pragma unroll 1
      for (int k0 = 0; k0 < H2; k0 += 64) {
        GLDS16(gA + k0, lAb);
        GLDS16(gA + k0 + (8 << 10), lAb + 8 * 128);
        GLDS16(gA + k0 + (16 << 10), lAb + 16 * 128);
        GLDS16(gA + k0 + (24 << 10), lAb + 24 * 128);
        if (w < 4) GLDS16(gB + k0, lBb);
        __syncthreads();

#pragma unroll
        for (int kk = 0; kk < 2; ++kk) {
          half8 bf = *(const half8*)((char*)sh.p2.B + (wt * 16 + m) * 128 +
                                     (((kk << 2) | q) ^ (m & 7)) * 16);
#pragma unroll
          for (int i = 0; i < 4; ++i) {
            half8 af =
                *(const half8*)((char*)sh.p2.A + (we * 64 + i * 16 + m) * 128 +
                                (((kk << 2) | q) ^ (m & 7)) * 16);
            acc[i] =
                __builtin_amdgcn_mfma_f32_16x16x32_f16(af, bf, acc[i], 0, 0, 0);
          }
        }
        __syncthreads();
      }

      // epilogue: +bias, tanh, pack fp16 (held only until end of this tc)
#pragma unroll
      for (int i = 0; i < 4; ++i) {
        half4 hv;
#pragma unroll
        for (int reg = 0; reg < 4; ++reg) {
          float bb = sh.p2.bias[e0 + we * 64 + i * 16 + q * 4 + reg];
          hv[reg] = (_Float16)tanh_fast(acc[i][reg] + bb);
        }
        uh[ec][i] = hv;
      }
    }

    // write u_it over own hhT rows [tb, tb+32) — all reads of them are done;
    // later t-chunks read disjoint rows, so no barrier needed.
#pragma unroll
    for (int ec = 0; ec < 4; ++ec)
#pragma unroll
      for (int i = 0; i < 4; ++i) {
        int tg = tb + wt * 16 + m;
        int eg = ec * 256 + we * 64 + i * 16 + q * 4;
        *(half4*)(hT + ((size_t)tg << 10) + eg) = uh[ec][i];
      }
  }
}

// ---------------------------------------------------------------------------
// Pre-pass: W fp32 -> fp16
// ---------------------------------------------------------------------------
__global__ __launch_bounds__(256) void wconv_kernel(const float* __restrict__ W,
                                                    _Float16* __restrict__ Wh) {
  int i = blockIdx.x * 256 + threadIdx.x;
  float4 v = ((const float4*)W)[i];
  half4 o = {(_Float16)v.x, (_Float16)v.y, (_Float16)v.z, (_Float16)v.w};
  ((half4*)Wh)[i] = o;
}

// ---------------------------------------------------------------------------
// scores[n,t] = sum_e u_it[n][t][e] * u_ws[n][e];  grid (4 t-chunks, 64 n)
// ---------------------------------------------------------------------------
__global__ __launch_bounds__(256) void scores_kernel(
    const _Float16* __restrict__ uit, const float* __restrict__ vbuf,
    const float* __restrict__ norm2, float* __restrict__ scores) {
  __shared__ float uws[1040];  // swizzled: addr = 4*tid + (tid>>4)
  int n = blockIdx.y, t0 = blockIdx.x * 128;
  int tid = threadIdx.x;

  float rs = 1.0f / fmaxf(sqrtf(norm2[n]), 1e-12f);
  float4 zv = ((const float4*)(vbuf + ((size_t)n << 10)))[tid];
  float4 sv = {zv.x * rs, zv.y * rs, zv.z * rs, zv.w * rs};
  *(float4*)(uws + 4 * tid + (tid >> 4)) = sv;
  __syncthreads();

  int g = tid & 15, rr = tid >> 4;
  const float* ub = uws + 65 * g;
#pragma unroll 1
  for (int pass = 0; pass < 8; ++pass) {
    int t = t0 + pass * 16 + rr;
    const half8* up = (const half8*)(uit + ((size_t)n << 19) +
                                     ((size_t)t << 10) + g * 64);
    float s = 0.f;
#pragma unroll
    for (int j = 0; j < 8; ++j) {
      half8 hv = up[j];
#pragma unroll
      for (int u = 0; u < 8; ++u) s += (float)hv[u] * ub[8 * j + u];
    }
    s += __shfl_xor(s, 1, 64);
    s += __shfl_xor(s, 2, 64);
    s += __shfl_xor(s, 4, 64);
    s += __shfl_xor(s, 8, 64);
    if (g == 0) scores[(size_t)n * TT + t] = s;
  }
}

// ---------------------------------------------------------------------------
// Fused softmax + weighted sum
// ---------------------------------------------------------------------------
__global__ __launch_bounds__(256) void out_kernel(
    const float* __restrict__ h, const float* __restrict__ scores,
    float* __restrict__ out) {
  int n = blockIdx.y;
  int ds = blockIdx.x;
  int tid = threadIdx.x;
  int w = tid >> 6, lane = tid & 63;

  __shared__ float sa[TT];
  __shared__ float wred[8];

  float s0 = scores[(size_t)n * TT + tid];
  float s1 = scores[(size_t)n * TT + 256 + tid];

  float mx = fmaxf(s0, s1);
#pragma unroll
  for (int off = 32; off >= 1; off >>= 1) mx = fmaxf(mx, __shfl_xor(mx, off, 64));
  if (lane == 0) wred[w] = mx;
  __syncthreads();
  mx = fmaxf(fmaxf(wred[0], wred[1]), fmaxf(wred[2], wred[3]));

  float e0 = __expf(s0 - mx);
  float e1 = __expf(s1 - mx);
  float ssum = e0 + e1;
#pragma unroll
  for (int off = 32; off >= 1; off >>= 1) ssum += __shfl_xor(ssum, off, 64);
  if (lane == 0) wred[4 + w] = ssum;
  __syncthreads();
  ssum = wred[4] + wred[5] + wred[6] + wred[7];
  float inv = 1.0f / ssum;
  sa[tid] = e0 * inv;
  sa[tid + 256] = e1 * inv;
  __syncthreads();

  int d0 = ds * 64 + w * 16;
  const float4* hb = reinterpret_cast<const float4*>(h + (size_t)n * H2 * TT);
#pragma unroll 1
  for (int rr = 0; rr < 16; ++rr) {
    int d = d0 + rr;
    const float4* hr = hb + (size_t)d * (TT / 4);
    float4 a4 = hr[lane];
    float4 b4 = hr[64 + lane];
    int t0 = 4 * lane;
    float acc = a4.x * sa[t0] + a4.y * sa[t0 + 1] + a4.z * sa[t0 + 2] +
                a4.w * sa[t0 + 3] + b4.x * sa[256 + t0] +
                b4.y * sa[256 + t0 + 1] + b4.z * sa[256 + t0 + 2] +
                b4.w * sa[256 + t0 + 3];
#pragma unroll
    for (int off = 1; off <= 32; off <<= 1) acc += __shfl_xor(acc, off, 64);
    if (lane == 0) out[(size_t)n * H2 + d] = acc;
  }
}

// ---------------------------------------------------------------------------
extern "C" void kernel_launch(void* const* d_in, const int* in_sizes, int n_in,
                              void* d_out, int out_size, void* d_ws, size_t ws_size,
                              hipStream_t stream) {
  const float* h    = (const float*)d_in[0];  // (64, 1024, 512)
  const float* W    = (const float*)d_in[1];  // (1024, 1024)
  const float* bias = (const float*)d_in[2];  // (1024,)
  const float* u0   = (const float*)d_in[3];  // (1024,)
  float* out = (float*)d_out;                 // (64, 1024)

  float* wsf    = (float*)d_ws;
  float* norm2  = wsf;                         // 64
  float* scores = wsf + 64;                    // 64*512
  float* vbuf   = wsf + 64 + (size_t)NSTEPS * TT;          // 64*1024
  _Float16* Wh  = (_Float16*)(vbuf + (size_t)NSTEPS * H2); // 1M halfs
  _Float16* hhT = Wh + (size_t)H2 * H2;        // 64 MB: hhT then u_it in-place

  // sentinel-init vbuf (the recurrence's poll target)
  hipMemsetAsync(vbuf, 0xFF, (size_t)NSTEPS * H2 * sizeof(float), stream);

  wconv_kernel<<<dim3(H2 * H2 / 1024), dim3(256), 0, stream>>>(W, Wh);

  mega_kernel<<<dim3(32 + 256), dim3(512), 0, stream>>>(W, bias, u0, h, Wh,
                                                        hhT, vbuf, norm2);

  scores_kernel<<<dim3(4, 64), dim3(256), 0, stream>>>(hhT, vbuf, norm2,
                                                       scores);

  out_kernel<<<dim3(16, 64), dim3(256), 0, stream>>>(h, scores, out);

  (void)in_sizes; (void)n_in; (void)out_size; (void)ws_size;
}

// Round 6
// 570.369 us; speedup vs baseline: 2.3834x; 2.3834x over previous
//
#include <hip/hip_runtime.h>
#include <cstdint>
#include <cstddef>

#define H2 1024
#define TT 512
#define NSTEPS 64
#define NRB 64  // recurrence blocks (16 rows each)

using floatx4 = __attribute__((__ext_vector_type__(4))) float;
using half8   = __attribute__((__ext_vector_type__(8))) _Float16;
using half4   = __attribute__((__ext_vector_type__(4))) _Float16;

__device__ __forceinline__ float tanh_fast(float x) {
  return 1.0f - 2.0f / (__expf(2.0f * x) + 1.0f);
}

#define SENTINEL 0xFFFFFFFFu  // -NaN bit pattern; never produced by the math

// ---------------------------------------------------------------------------
// Mega kernel, 2112 blocks x 256 threads.
//  blocks 0..63   : recurrence. Wave w owns rows r0 = bid*16 + 4w .. +3; each
//                   lane holds 16 z-floats; sentinel-poll on vbuf (agent-scope
//                   loads -> LLC). Proven 183us protocol from R5.
//  blocks 64..2111: round-1 GEMM body (proven 184us): 128x128 (e,t) tile,
//                   BK=32, padded LDS [128][40], inline fp32->fp16 staging.
//                   Epilogue: tanh(acc+bias) -> fp16 u_it[n][t][e]. NO
//                   dependency on recurrence -> blocks always retire ->
//                   recurrence blocks always get dispatched -> no deadlock.
// ---------------------------------------------------------------------------
__global__ __launch_bounds__(256) void mega_kernel(
    const float* __restrict__ W, const float* __restrict__ bias,
    const float* __restrict__ u0, const float* __restrict__ h,
    float* __restrict__ vbuf, float* __restrict__ norm2,
    _Float16* __restrict__ uit) {
  int tid = threadIdx.x;

  if (blockIdx.x < NRB) {
    // ================= RECURRENCE ROLE =================
    int bid = blockIdx.x;
    int w = tid >> 6, lane = tid & 63;
    int r0 = bid * 16 + w * 4;  // wave owns rows r0..r0+3

    float4 wreg[4][4];
#pragma unroll
    for (int p = 0; p < 4; ++p) {
      const float4* wr =
          (const float4*)(W + ((size_t)(r0 + p) << 10) + 16 * lane);
#pragma unroll
      for (int j = 0; j < 4; ++j) wreg[p][j] = wr[j];
    }
    float bl = bias[r0 + (lane & 3)];

    for (int i = 0; i < NSTEPS; ++i) {
      float4 z[4];
      if (i == 0) {
        const float4* up = (const float4*)(u0 + 16 * lane);
#pragma unroll
        for (int j = 0; j < 4; ++j) z[j] = up[j];
      } else {
        const unsigned long long* src =
            (const unsigned long long*)(vbuf + (((size_t)(i - 1)) << 10) +
                                        16 * lane);
        unsigned long long v[8];
        for (;;) {
          bool good = true;
#pragma unroll
          for (int j = 0; j < 8; ++j) {
            v[j] = __hip_atomic_load(src + j, __ATOMIC_RELAXED,
                                     __HIP_MEMORY_SCOPE_AGENT);
            if ((unsigned)(v[j]) == SENTINEL ||
                (unsigned)(v[j] >> 32) == SENTINEL)
              good = false;
          }
          if (__ballot(good) == ~0ull) break;
          __builtin_amdgcn_s_sleep(2);
        }
#pragma unroll
        for (int j = 0; j < 4; ++j) {
          union { unsigned long long u[2]; float4 f; } cv;
          cv.u[0] = v[2 * j];
          cv.u[1] = v[2 * j + 1];
          z[j] = cv.f;
        }
      }

      float sq = 0.f, d0 = 0.f, d1 = 0.f, d2 = 0.f, d3 = 0.f;
#pragma unroll
      for (int j = 0; j < 4; ++j) {
        float4 c = z[j];
        sq += c.x * c.x + c.y * c.y + c.z * c.z + c.w * c.w;
        float4 a;
        a = wreg[0][j]; d0 += a.x * c.x + a.y * c.y + a.z * c.z + a.w * c.w;
        a = wreg[1][j]; d1 += a.x * c.x + a.y * c.y + a.z * c.z + a.w * c.w;
        a = wreg[2][j]; d2 += a.x * c.x + a.y * c.y + a.z * c.z + a.w * c.w;
        a = wreg[3][j]; d3 += a.x * c.x + a.y * c.y + a.z * c.z + a.w * c.w;
      }
#pragma unroll
      for (int off = 1; off <= 32; off <<= 1) {
        sq += __shfl_xor(sq, off, 64);
        d0 += __shfl_xor(d0, off, 64);
        d1 += __shfl_xor(d1, off, 64);
        d2 += __shfl_xor(d2, off, 64);
        d3 += __shfl_xor(d3, off, 64);
      }
      float rs = (i == 0) ? 1.0f : 1.0f / fmaxf(sqrtf(sq), 1e-12f);
      if (bid == 0 && w == 0 && lane == 0 && i > 0) norm2[i - 1] = sq;

      if (lane < 4) {
        float d = (lane == 0) ? d0 : (lane == 1) ? d1 : (lane == 2) ? d2 : d3;
        float v = d * rs + bl;
        __hip_atomic_store(vbuf + (((size_t)i) << 10) + r0 + lane, v,
                           __ATOMIC_RELAXED, __HIP_MEMORY_SCOPE_AGENT);
      }
    }

    // block 0 / wave 0: compute and persist ||z_63||^2 (scores needs it)
    if (bid == 0 && w == 0) {
      const unsigned long long* src =
          (const unsigned long long*)(vbuf + (((size_t)(NSTEPS - 1)) << 10) +
                                      16 * lane);
      unsigned long long v[8];
      for (;;) {
        bool good = true;
#pragma unroll
        for (int j = 0; j < 8; ++j) {
          v[j] = __hip_atomic_load(src + j, __ATOMIC_RELAXED,
                                   __HIP_MEMORY_SCOPE_AGENT);
          if ((unsigned)(v[j]) == SENTINEL ||
              (unsigned)(v[j] >> 32) == SENTINEL)
            good = false;
        }
        if (__ballot(good) == ~0ull) break;
        __builtin_amdgcn_s_sleep(2);
      }
      float sq = 0.f;
#pragma unroll
      for (int j = 0; j < 8; ++j) {
        union { unsigned long long u; float f[2]; } cv;
        cv.u = v[j];
        sq += cv.f[0] * cv.f[0] + cv.f[1] * cv.f[1];
      }
#pragma unroll
      for (int off = 1; off <= 32; off <<= 1) sq += __shfl_xor(sq, off, 64);
      if (lane == 0) norm2[NSTEPS - 1] = sq;
    }
    return;
  }

  // ================= GEMM ROLE (round-1 proven body) =================
  int gb = blockIdx.x - NRB;       // 0..2047
  int n = gb >> 5;                 // 64 n, 32 tiles each (adjacent -> L2 reuse)
  int rem = gb & 31;
  int e_base = (rem & 7) * 128;
  int t_base = (rem >> 3) * 128;

  int lane = tid & 63, w = tid >> 6;
  int q = lane >> 4, m = lane & 15;
  int eoff = (w & 1) * 64, toff = (w >> 1) * 64;

  __shared__ __align__(16) _Float16 Ash[128][40];  // [e][k], pad->40
  __shared__ __align__(16) _Float16 Bsh[128][40];  // [t][k] (transposed)

  floatx4 zero = {0.f, 0.f, 0.f, 0.f};
  floatx4 acc[4][4];
#pragma unroll
  for (int i = 0; i < 4; ++i)
#pragma unroll
    for (int j = 0; j < 4; ++j) acc[i][j] = zero;

  const float* hb = h + (size_t)n * H2 * TT + t_base;
  int r0 = tid >> 3, c4 = (tid & 7) << 2;
  int kk4 = (tid >> 5) << 2, tl = tid & 31;

  for (int k0 = 0; k0 < H2; k0 += 32) {
    // stage A: W[e_base..+128)[k0..+32) -> fp16
#pragma unroll
    for (int p = 0; p < 4; ++p) {
      int r = p * 32 + r0;
      const float* wp = W + (size_t)(e_base + r) * H2 + k0 + c4;
      float4 wv = *reinterpret_cast<const float4*>(wp);
      half4 hv = {(_Float16)wv.x, (_Float16)wv.y, (_Float16)wv.z,
                  (_Float16)wv.w};
      *reinterpret_cast<half4*>(&Ash[r][c4]) = hv;
    }
    // stage B: h[n][k0..+32)[t_base..+128) -> fp16 (transposed)
    const float* hp = hb + (size_t)(k0 + kk4) * TT;
#pragma unroll
    for (int jj = 0; jj < 4; ++jj) {
      int t = tl + 32 * jj;
      float x0 = hp[t];
      float x1 = hp[TT + t];
      float x2 = hp[2 * TT + t];
      float x3 = hp[3 * TT + t];
      half4 hv = {(_Float16)x0, (_Float16)x1, (_Float16)x2, (_Float16)x3};
      *reinterpret_cast<half4*>(&Bsh[t][kk4]) = hv;
    }
    __syncthreads();

    half8 af[4], bf[4];
#pragma unroll
    for (int i = 0; i < 4; ++i)
      af[i] = *reinterpret_cast<const half8*>(&Ash[eoff + i * 16 + m][q * 8]);
#pragma unroll
    for (int j = 0; j < 4; ++j)
      bf[j] = *reinterpret_cast<const half8*>(&Bsh[toff + j * 16 + m][q * 8]);
#pragma unroll
    for (int i = 0; i < 4; ++i)
#pragma unroll
      for (int j = 0; j < 4; ++j)
        acc[i][j] = __builtin_amdgcn_mfma_f32_16x16x32_f16(af[i], bf[j],
                                                           acc[i][j], 0, 0, 0);
    __syncthreads();
  }

  // epilogue: +bias, tanh, fp16 store of u_it[n][t][e]  (no recur dependency)
  float* bloc = reinterpret_cast<float*>(&Ash[0][0]);
  if (tid < 128) bloc[tid] = bias[e_base + tid];
  __syncthreads();

  _Float16* un = uit + (((size_t)n) << 19);
#pragma unroll
  for (int i = 0; i < 4; ++i) {
#pragma unroll
    for (int j = 0; j < 4; ++j) {
      int t = t_base + toff + j * 16 + m;
      int e = eoff + i * 16 + q * 4;
      half4 hv;
#pragma unroll
      for (int reg = 0; reg < 4; ++reg)
        hv[reg] = (_Float16)tanh_fast(acc[i][j][reg] + bloc[e + reg]);
      *(half4*)(un + ((size_t)t << 10) + e_base + e) = hv;
    }
  }
}

// ---------------------------------------------------------------------------
// scores[n,t] = sum_e u_it[n][t][e] * u_ws[n][e];  grid (4 t-chunks, 64 n)
// ---------------------------------------------------------------------------
__global__ __launch_bounds__(256) void scores_kernel(
    const _Float16* __restrict__ uit, const float* __restrict__ vbuf,
    const float* __restrict__ norm2, float* __restrict__ scores) {
  __shared__ float uws[1040];  // swizzled: addr = i + (i>>6)
  int n = blockIdx.y, t0 = blockIdx.x * 128;
  int tid = threadIdx.x;

  float rs = 1.0f / fmaxf(sqrtf(norm2[n]), 1e-12f);
  float4 zv = ((const float4*)(vbuf + ((size_t)n << 10)))[tid];
  float4 sv = {zv.x * rs, zv.y * rs, zv.z * rs, zv.w * rs};
  *(float4*)(uws + 4 * tid + (tid >> 4)) = sv;
  __syncthreads();

  int g = tid & 15, rr = tid >> 4;
  const float* ub = uws + 65 * g;
#pragma unroll 1
  for (int pass = 0; pass < 8; ++pass) {
    int t = t0 + pass * 16 + rr;
    const half8* up = (const half8*)(uit + ((size_t)n << 19) +
                                     ((size_t)t << 10) + g * 64);
    float s = 0.f;
#pragma unroll
    for (int j = 0; j < 8; ++j) {
      half8 hv = up[j];
#pragma unroll
      for (int u = 0; u < 8; ++u) s += (float)hv[u] * ub[8 * j + u];
    }
    s += __shfl_xor(s, 1, 64);
    s += __shfl_xor(s, 2, 64);
    s += __shfl_xor(s, 4, 64);
    s += __shfl_xor(s, 8, 64);
    if (g == 0) scores[(size_t)n * TT + t] = s;
  }
}

// ---------------------------------------------------------------------------
// Fused softmax + weighted sum
// ---------------------------------------------------------------------------
__global__ __launch_bounds__(256) void out_kernel(
    const float* __restrict__ h, const float* __restrict__ scores,
    float* __restrict__ out) {
  int n = blockIdx.y;
  int ds = blockIdx.x;
  int tid = threadIdx.x;
  int w = tid >> 6, lane = tid & 63;

  __shared__ float sa[TT];
  __shared__ float wred[8];

  float s0 = scores[(size_t)n * TT + tid];
  float s1 = scores[(size_t)n * TT + 256 + tid];

  float mx = fmaxf(s0, s1);
#pragma unroll
  for (int off = 32; off >= 1; off >>= 1) mx = fmaxf(mx, __shfl_xor(mx, off, 64));
  if (lane == 0) wred[w] = mx;
  __syncthreads();
  mx = fmaxf(fmaxf(wred[0], wred[1]), fmaxf(wred[2], wred[3]));

  float e0 = __expf(s0 - mx);
  float e1 = __expf(s1 - mx);
  float ssum = e0 + e1;
#pragma unroll
  for (int off = 32; off >= 1; off >>= 1) ssum += __shfl_xor(ssum, off, 64);
  if (lane == 0) wred[4 + w] = ssum;
  __syncthreads();
  ssum = wred[4] + wred[5] + wred[6] + wred[7];
  float inv = 1.0f / ssum;
  sa[tid] = e0 * inv;
  sa[tid + 256] = e1 * inv;
  __syncthreads();

  int d0 = ds * 64 + w * 16;
  const float4* hb = reinterpret_cast<const float4*>(h + (size_t)n * H2 * TT);
#pragma unroll 1
  for (int rr = 0; rr < 16; ++rr) {
    int d = d0 + rr;
    const float4* hr = hb + (size_t)d * (TT / 4);
    float4 a4 = hr[lane];
    float4 b4 = hr[64 + lane];
    int t0 = 4 * lane;
    float acc = a4.x * sa[t0] + a4.y * sa[t0 + 1] + a4.z * sa[t0 + 2] +
                a4.w * sa[t0 + 3] + b4.x * sa[256 + t0] +
                b4.y * sa[256 + t0 + 1] + b4.z * sa[256 + t0 + 2] +
                b4.w * sa[256 + t0 + 3];
#pragma unroll
    for (int off = 1; off <= 32; off <<= 1) acc += __shfl_xor(acc, off, 64);
    if (lane == 0) out[(size_t)n * H2 + d] = acc;
  }
}

// ---------------------------------------------------------------------------
extern "C" void kernel_launch(void* const* d_in, const int* in_sizes, int n_in,
                              void* d_out, int out_size, void* d_ws, size_t ws_size,
                              hipStream_t stream) {
  const float* h    = (const float*)d_in[0];  // (64, 1024, 512)
  const float* W    = (const float*)d_in[1];  // (1024, 1024)
  const float* bias = (const float*)d_in[2];  // (1024,)
  const float* u0   = (const float*)d_in[3];  // (1024,)
  float* out = (float*)d_out;                 // (64, 1024)

  float* wsf    = (float*)d_ws;
  float* norm2  = wsf;                                   // 64
  float* scores = wsf + 64;                              // 64*512
  float* vbuf   = wsf + 64 + (size_t)NSTEPS * TT;        // 64*1024
  _Float16* uit = (_Float16*)(vbuf + (size_t)NSTEPS * H2);  // 64 MB

  // sentinel-init vbuf (the recurrence's poll target)
  hipMemsetAsync(vbuf, 0xFF, (size_t)NSTEPS * H2 * sizeof(float), stream);

  mega_kernel<<<dim3(NRB + 2048), dim3(256), 0, stream>>>(W, bias, u0, h,
                                                          vbuf, norm2, uit);

  scores_kernel<<<dim3(4, 64), dim3(256), 0, stream>>>(uit, vbuf, norm2,
                                                       scores);

  out_kernel<<<dim3(16, 64), dim3(256), 0, stream>>>(h, scores, out);

  (void)in_sizes; (void)n_in; (void)out_size; (void)ws_size;
}